// Round 6
// baseline (197.650 us; speedup 1.0000x reference)
//
#include <hip/hip_runtime.h>
#include <math.h>

// STRNN: B=16, S=128, D=64, K=64, H=128, NSLOT+1=97 slots.
//
// Pipeline (all f32), no contended global atomics:
//  k_hist1    : per-block LDS histograms of t-slot / d-slot / per-(b,i) counts
//  k_scan_all : exclusive scans -> per-(bin,block) bases + OFF_T/OFF_D/OFF_B
//  k_scatter  : one pass; LDS cursors; emits t-sorted entries, d-sorted refs, Y slots
//  k_phaseA   : per t-bucket GEMM  xt = x[b,j] @ Tw[t]   (Tw in LDS) -> XT[tpos][64]
//  k_phaseB   : per d-bucket GEMM  y = xt @ Dw[d] (Dw in LDS) -> Y[dstpos][128]
//  k_reduce   : XC[b,i,:] = sum of its contiguous Y rows
//  k_recur    : h = sigmoid(XC[b,i] + h@Wh); h lives in REGISTERS (1 elem/lane),
//               broadcast via v_readlane -> FMA with SGPR operand; W in VGPRs
//               (w[64]/thread, no spill); only ~6 tiny LDS ops + 2 barriers/step.
//
// ws requirement: ~104.3 MB for the atomic-free path (guarded; fallback = atomicAdd XC).

#define B_ 16
#define S_ 128
#define D_ 64
#define K_ 64
#define H_ 128
#define NS 97
#define MAXE 132096  // B * S*(S+1)/2  (upper bound on valid triples)

// u32/f32-index offsets into ws
#define XC_OFF 0                  // f32 [2048][128]
#define BH_T   262144             // u32 [97][256]  per-(bin,block) hist -> bases
#define BH_D   (BH_T + 24832)     // u32 [97][256]
#define CNT_T  (BH_D + 24832)     // u32 [97]
#define CNT_D  (CNT_T + 97)       // u32 [97]
#define CNT_B  (CNT_D + 97)       // u32 [2048]
#define OFF_T  (CNT_B + 2048)     // u32 [98] (last = total)
#define OFF_D  (OFF_T + 98)       // u32 [98]
#define OFF_B  (OFF_D + 98)       // u32 [2049]
#define ENT_T  316296             // u32 [MAXE] packed: b|i<<4|j<<11|t<<18|d<<25 (16B-aligned)
#define ENT_DX (ENT_T + MAXE)     // u32 [MAXE] xt-row index (t-sorted pos)
#define ENT_DP (ENT_DX + MAXE)    // u32 [MAXE] Y-row (dst-sorted pos) [or dst in fallback]
#define XT_OFF (ENT_DP + MAXE)    // f32 [MAXE][64]
#define Y_OFF  (XT_OFF + MAXE * 64)            // f32 [MAXE][128]
#define NEED_BYTES ((size_t)(Y_OFF + (size_t)MAXE * 128) * 4)

// ---- binning: 256 blocks x 1024 elements (8 full (b,i) rows per block) ----

__global__ __launch_bounds__(256) void k_hist1(const int* __restrict__ tc,
                                               const int* __restrict__ dc,
                                               const int* __restrict__ mk,
                                               unsigned* wsi) {
    __shared__ unsigned ht[NS], hd[NS], hb[8];
    int tid = threadIdx.x, blk = blockIdx.x;
    if (tid < NS) { ht[tid] = 0; hd[tid] = 0; }
    if (tid < 8) hb[tid] = 0;
    __syncthreads();
    int base = blk * 1024;
    #pragma unroll
    for (int u = 0; u < 4; u++) {
        int idx = base + tid + u * 256;
        int i = (idx >> 7) & 127, j = idx & 127;
        if (j <= i && mk[idx] != 0) {
            atomicAdd(&ht[tc[idx]], 1u);
            atomicAdd(&hd[dc[idx]], 1u);
            atomicAdd(&hb[(idx >> 7) & 7], 1u);
        }
    }
    __syncthreads();
    if (tid < NS) {
        wsi[BH_T + tid * 256 + blk] = ht[tid];
        wsi[BH_D + tid * 256 + blk] = hd[tid];
    }
    if (tid < 8) wsi[CNT_B + blk * 8 + tid] = hb[tid];
}

template <int CH>
__device__ unsigned scan_region(unsigned* in, unsigned* out, int L, unsigned* s) {
    int tid = threadIdx.x;
    unsigned loc[CH], sum = 0;
    #pragma unroll
    for (int k = 0; k < CH; k++) {
        int idx = tid * CH + k;
        loc[k] = (idx < L) ? in[idx] : 0u;
        sum += loc[k];
    }
    s[tid] = sum;
    __syncthreads();
    for (int o = 1; o < 1024; o <<= 1) {
        unsigned a = (tid >= o) ? s[tid - o] : 0u;
        __syncthreads();
        s[tid] += a;
        __syncthreads();
    }
    unsigned total = s[1023];
    unsigned run = s[tid] - sum;
    __syncthreads();
    #pragma unroll
    for (int k = 0; k < CH; k++) {
        int idx = tid * CH + k;
        if (idx < L) { out[idx] = run; run += loc[k]; }
    }
    __syncthreads();
    return total;
}

__global__ __launch_bounds__(1024) void k_scan_all(unsigned* wsi) {
    __shared__ unsigned s[1024];
    int tid = threadIdx.x;

    unsigned totT = scan_region<25>(wsi + BH_T, wsi + BH_T, NS * 256, s);
    if (tid < NS) {
        unsigned b0 = wsi[BH_T + tid * 256];
        unsigned b1 = (tid < NS - 1) ? wsi[BH_T + (tid + 1) * 256] : totT;
        wsi[OFF_T + tid] = b0;
        wsi[CNT_T + tid] = b1 - b0;
    }
    if (tid == 0) wsi[OFF_T + NS] = totT;
    __syncthreads();

    unsigned totD = scan_region<25>(wsi + BH_D, wsi + BH_D, NS * 256, s);
    if (tid < NS) {
        unsigned b0 = wsi[BH_D + tid * 256];
        unsigned b1 = (tid < NS - 1) ? wsi[BH_D + (tid + 1) * 256] : totD;
        wsi[OFF_D + tid] = b0;
        wsi[CNT_D + tid] = b1 - b0;
    }
    if (tid == 0) wsi[OFF_D + NS] = totD;
    __syncthreads();

    unsigned totB = scan_region<2>(wsi + CNT_B, wsi + OFF_B, 2048, s);
    if (tid == 0) wsi[OFF_B + 2048] = totB;
}

__global__ __launch_bounds__(256) void k_scatter(const int* __restrict__ tc,
                                                 const int* __restrict__ dc,
                                                 const int* __restrict__ mk,
                                                 unsigned* wsi, int useY) {
    __shared__ unsigned ct[NS], cd[NS], cb[8];
    int tid = threadIdx.x, blk = blockIdx.x;
    if (tid < NS) {
        ct[tid] = wsi[BH_T + tid * 256 + blk];
        cd[tid] = wsi[BH_D + tid * 256 + blk];
    }
    if (tid < 8) cb[tid] = wsi[OFF_B + blk * 8 + tid];
    __syncthreads();
    int base = blk * 1024;
    #pragma unroll
    for (int u = 0; u < 4; u++) {
        int idx = base + tid + u * 256;
        int i = (idx >> 7) & 127, j = idx & 127, b = idx >> 14;
        if (j <= i && mk[idx] != 0) {
            unsigned t = (unsigned)tc[idx], d = (unsigned)dc[idx];
            unsigned tpos = atomicAdd(&ct[t], 1u);
            wsi[ENT_T + tpos] = (unsigned)b | ((unsigned)i << 4) | ((unsigned)j << 11)
                              | (t << 18) | (d << 25);
            unsigned dpos = atomicAdd(&cd[d], 1u);
            unsigned yp = useY ? atomicAdd(&cb[(idx >> 7) & 7], 1u) : (unsigned)(idx >> 7);
            wsi[ENT_DX + dpos] = tpos;
            wsi[ENT_DP + dpos] = yp;
        }
    }
}

// phase A: xt[entry][kk] = sum_dd x[b,j][dd] * Tw[t][dd][kk]
__global__ __launch_bounds__(256) void k_phaseA(const float* __restrict__ x,
                                                const float* __restrict__ tw,
                                                unsigned* wsi, float* wsf) {
    int t = blockIdx.x, c = blockIdx.y;
    int rows = (int)wsi[CNT_T + t] - c * 128;
    if (rows <= 0) return;
    if (rows > 128) rows = 128;
    unsigned base = wsi[OFF_T + t] + c * 128;

    __shared__ float stw[4096];     // Tw[t] row-major [dd][kk]
    __shared__ float sx[8192];      // x rows, XOR-swizzled in 4-float units
    __shared__ unsigned ent[128];
    int tid = threadIdx.x;

    const float4* twg = (const float4*)(tw + t * 4096);
    float4* stw4 = (float4*)stw;
    #pragma unroll
    for (int q = 0; q < 4; q++) stw4[q * 256 + tid] = twg[q * 256 + tid];
    if (tid < 128) ent[tid] = (tid < rows) ? wsi[ENT_T + base + tid] : 0u;
    __syncthreads();

    int lane16 = tid & 15, rquot = tid >> 4;
    #pragma unroll
    for (int p = 0; p < 8; p++) {
        int r = p * 16 + rquot;
        float4 v = make_float4(0.f, 0.f, 0.f, 0.f);
        if (r < rows) {
            unsigned e = ent[r];
            int b = e & 15, j = (e >> 11) & 127;
            v = *(const float4*)(x + (b * S_ + j) * D_ + lane16 * 4);
        }
        int col4 = lane16 ^ (r & 15);
        float* dst = &sx[r * 64 + col4 * 4];
        dst[0] = v.x; dst[1] = v.y; dst[2] = v.z; dst[3] = v.w;
    }
    __syncthreads();

    int rgrp = tid & 15, cgrp = tid >> 4;   // 8 rows (rgrp+16i) x 4 cols (cgrp*4..)
    float4 acc[8];
    #pragma unroll
    for (int i = 0; i < 8; i++) acc[i] = make_float4(0.f, 0.f, 0.f, 0.f);
    #pragma unroll 4
    for (int dd = 0; dd < 64; dd++) {
        float4 w = stw4[dd * 16 + cgrp];
        int s_idx = (((dd >> 2) ^ rgrp) << 2) + (dd & 3);
        #pragma unroll
        for (int i = 0; i < 8; i++) {
            float a = sx[(rgrp + 16 * i) * 64 + s_idx];
            acc[i].x += a * w.x; acc[i].y += a * w.y;
            acc[i].z += a * w.z; acc[i].w += a * w.w;
        }
    }
    float* XT = wsf + XT_OFF;
    #pragma unroll
    for (int i = 0; i < 8; i++) {
        int r = rgrp + 16 * i;
        if (r < rows) *(float4*)(XT + (size_t)(base + r) * 64 + cgrp * 4) = acc[i];
    }
}

// phase B: y[hh] = sum_kk xt[entry][kk] * Dw[d][kk][hh]; write to Y[dstpos] (or atomic XC)
__global__ __launch_bounds__(256) void k_phaseB(const float* __restrict__ dw,
                                                unsigned* wsi, float* wsf, int useY) {
    int d = blockIdx.x, c = blockIdx.y;
    int rows = (int)wsi[CNT_D + d] - c * 128;
    if (rows <= 0) return;
    if (rows > 128) rows = 128;
    unsigned base = wsi[OFF_D + d] + c * 128;

    __shared__ float sdw[8192];     // Dw[d] row-major [kk][hh]
    __shared__ float sx[8192];      // xt rows, swizzled
    __shared__ unsigned entx[128];
    __shared__ unsigned entp[128];
    int tid = threadIdx.x;

    const float4* dwg = (const float4*)(dw + (size_t)d * 8192);
    float4* sdw4 = (float4*)sdw;
    #pragma unroll
    for (int q = 0; q < 8; q++) sdw4[q * 256 + tid] = dwg[q * 256 + tid];
    if (tid < 128) {
        entx[tid] = (tid < rows) ? wsi[ENT_DX + base + tid] : 0u;
        entp[tid] = (tid < rows) ? wsi[ENT_DP + base + tid] : 0u;
    }
    __syncthreads();

    const float* XT = wsf + XT_OFF;
    int lane16 = tid & 15, rquot = tid >> 4;
    #pragma unroll
    for (int p = 0; p < 8; p++) {
        int r = p * 16 + rquot;
        float4 v = make_float4(0.f, 0.f, 0.f, 0.f);
        if (r < rows) {
            unsigned pos = entx[r];
            v = *(const float4*)(XT + (size_t)pos * 64 + lane16 * 4);
        }
        int col4 = lane16 ^ (r & 15);
        float* dst2 = &sx[r * 64 + col4 * 4];
        dst2[0] = v.x; dst2[1] = v.y; dst2[2] = v.z; dst2[3] = v.w;
    }
    __syncthreads();

    int rgrp = tid & 15, cgrp = tid >> 4;   // 8 rows x 8 cols (cgrp*8..)
    float4 a0[8], a1[8];
    #pragma unroll
    for (int i = 0; i < 8; i++) {
        a0[i] = make_float4(0.f, 0.f, 0.f, 0.f);
        a1[i] = make_float4(0.f, 0.f, 0.f, 0.f);
    }
    #pragma unroll 2
    for (int kk = 0; kk < 64; kk++) {
        float4 w0 = sdw4[kk * 32 + cgrp * 2];
        float4 w1 = sdw4[kk * 32 + cgrp * 2 + 1];
        int s_idx = (((kk >> 2) ^ rgrp) << 2) + (kk & 3);
        #pragma unroll
        for (int i = 0; i < 8; i++) {
            float a = sx[(rgrp + 16 * i) * 64 + s_idx];
            a0[i].x += a * w0.x; a0[i].y += a * w0.y; a0[i].z += a * w0.z; a0[i].w += a * w0.w;
            a1[i].x += a * w1.x; a1[i].y += a * w1.y; a1[i].z += a * w1.z; a1[i].w += a * w1.w;
        }
    }
    if (useY) {
        float* Y = wsf + Y_OFF;
        #pragma unroll
        for (int i = 0; i < 8; i++) {
            int r = rgrp + 16 * i;
            if (r < rows) {
                float* p = Y + (size_t)entp[r] * 128 + cgrp * 8;
                *(float4*)p = a0[i];
                *(float4*)(p + 4) = a1[i];
            }
        }
    } else {
        float* XC = wsf + XC_OFF;
        #pragma unroll
        for (int i = 0; i < 8; i++) {
            int r = rgrp + 16 * i;
            if (r < rows) {
                float* p = XC + (size_t)entp[r] * 128 + cgrp * 8;
                atomicAdd(p + 0, a0[i].x); atomicAdd(p + 1, a0[i].y);
                atomicAdd(p + 2, a0[i].z); atomicAdd(p + 3, a0[i].w);
                atomicAdd(p + 4, a1[i].x); atomicAdd(p + 5, a1[i].y);
                atomicAdd(p + 6, a1[i].z); atomicAdd(p + 7, a1[i].w);
            }
        }
    }
}

// XC[b,i,:] = sum of this (b,i)'s contiguous Y rows
__global__ __launch_bounds__(128) void k_reduce(unsigned* wsi, float* wsf) {
    int bi = blockIdx.x, tid = threadIdx.x;
    unsigned n = wsi[CNT_B + bi], off = wsi[OFF_B + bi];
    const float* Yp = wsf + Y_OFF + (size_t)off * 128 + tid;
    float a0 = 0.f, a1 = 0.f, a2 = 0.f, a3 = 0.f;
    unsigned e = 0;
    for (; e + 4 <= n; e += 4) {
        a0 += Yp[(size_t)e * 128];
        a1 += Yp[(size_t)(e + 1) * 128];
        a2 += Yp[(size_t)(e + 2) * 128];
        a3 += Yp[(size_t)(e + 3) * 128];
    }
    for (; e < n; e++) a0 += Yp[(size_t)e * 128];
    wsf[XC_OFF + (size_t)bi * 128 + tid] = (a0 + a1) + (a2 + a3);
}

// recurrence: h_new = sigmoid(XC[b,i] + h @ Wh); one block (256 thr = 4 waves) per b.
// Wave = (colhalf, khalf): lane owns col = colhalf*64+lane, holds w[64] =
// Wh[khalf*64+k][col] in VGPRs and h_reg = h[khalf*64+lane] in ONE register.
// Dot product: 64 x (v_readlane -> SGPR) * w[k] FMA; no LDS on the K axis.
// Per step: ~6 small LDS ops (khalf-partial combine + h redistribute) + 2 barriers.
__global__ __launch_bounds__(256) void k_recur(const float* __restrict__ hw,
                                               const float* __restrict__ wsf,
                                               float* __restrict__ out) {
    int b = blockIdx.x;
    __shared__ float swh[16384];    // staging for weight transpose (used once)
    __shared__ float part[128];     // khalf=1 partial sums
    __shared__ float h_ld[128];     // current h (redistribution)
    int tid = threadIdx.x;
    int lane = tid & 63;
    int wv = tid >> 6;              // wave id
    int khalf = wv & 1, colhalf = wv >> 1;
    int col = colhalf * 64 + lane;
    int k0 = khalf * 64;

    const float4* hwg = (const float4*)hw;
    float4* swh4 = (float4*)swh;
    #pragma unroll
    for (int q = 0; q < 16; q++) swh4[q * 256 + tid] = hwg[q * 256 + tid];
    if (tid < 128) h_ld[tid] = 0.f;
    __syncthreads();
    float w[64];
    #pragma unroll
    for (int k = 0; k < 64; k++) w[k] = swh[(k0 + k) * 128 + col];

    float h_reg = 0.f;              // h[k0 + lane]

    const float* XC = wsf + XC_OFF + (size_t)b * 128 * 128;
    float xc_next = (khalf == 0) ? XC[col] : 0.f;   // row 0 prefetch
    for (int i = 0; i < 128; i++) {
        float xc = xc_next;
        if (khalf == 0 && i < 127) xc_next = XC[(i + 1) * 128 + col];
        // dot: acc = sum_k h[k0+k] * w[k], h broadcast via readlane (static idx)
        float acc0 = 0.f, acc1 = 0.f, acc2 = 0.f, acc3 = 0.f;
        int hbits = __float_as_int(h_reg);
        #pragma unroll
        for (int k = 0; k < 64; k += 4) {
            acc0 += __int_as_float(__builtin_amdgcn_readlane(hbits, k + 0)) * w[k + 0];
            acc1 += __int_as_float(__builtin_amdgcn_readlane(hbits, k + 1)) * w[k + 1];
            acc2 += __int_as_float(__builtin_amdgcn_readlane(hbits, k + 2)) * w[k + 2];
            acc3 += __int_as_float(__builtin_amdgcn_readlane(hbits, k + 3)) * w[k + 3];
        }
        float acc = (acc0 + acc1) + (acc2 + acc3);
        if (khalf == 1) part[col] = acc;
        __syncthreads();
        if (khalf == 0) {
            float val = xc + acc + part[col];
            val = 1.f / (1.f + __expf(-val));
            h_ld[col] = val;
            out[(size_t)(b * 128 + i) * 128 + col] = val;
        }
        __syncthreads();
        h_reg = h_ld[k0 + lane];
    }
    if (tid < 128) out[(size_t)B_ * S_ * H_ + b * 128 + tid] = h_ld[tid];
}

extern "C" void kernel_launch(void* const* d_in, const int* in_sizes, int n_in,
                              void* d_out, int out_size, void* d_ws, size_t ws_size,
                              hipStream_t stream) {
    const float* x  = (const float*)d_in[0];
    const int*   tc = (const int*)d_in[1];
    const int*   dc = (const int*)d_in[2];
    const int*   mk = (const int*)d_in[3];   // bool masks pushed as int32
    const float* tw = (const float*)d_in[4];
    const float* dw = (const float*)d_in[5];
    const float* hw = (const float*)d_in[6];
    float*    out = (float*)d_out;
    float*    wsf = (float*)d_ws;
    unsigned* wsi = (unsigned*)d_ws;
    char*     wsb = (char*)d_ws;

    int useY = (ws_size >= NEED_BYTES) ? 1 : 0;
    if (!useY)  // fallback path accumulates into XC with atomics -> needs zeroed XC
        hipMemsetAsync(wsb, 0, (size_t)262144 * 4, stream);

    k_hist1<<<dim3(256), dim3(256), 0, stream>>>(tc, dc, mk, wsi);
    k_scan_all<<<dim3(1), dim3(1024), 0, stream>>>(wsi);
    k_scatter<<<dim3(256), dim3(256), 0, stream>>>(tc, dc, mk, wsi, useY);
    k_phaseA<<<dim3(NS, 16), dim3(256), 0, stream>>>(x, tw, wsi, wsf);
    k_phaseB<<<dim3(NS, 16), dim3(256), 0, stream>>>(dw, wsi, wsf, useY);
    if (useY) k_reduce<<<dim3(2048), dim3(128), 0, stream>>>(wsi, wsf);
    k_recur<<<dim3(16), dim3(256), 0, stream>>>(hw, wsf, out);
}

// Round 7
// 165.219 us; speedup vs baseline: 1.1963x; 1.1963x over previous
//
#include <hip/hip_runtime.h>
#include <math.h>

// STRNN: B=16, S=128, D=64, K=64, H=128, NSLOT+1=97 slots.
//
// Pipeline (all f32 except recurrence dot in f16x2->f32 dot2):
//  k_hist1    : per-block LDS histograms of t-slot / d-slot / per-(b,i) counts
//  k_scan_all : exclusive scans -> per-(bin,block) bases + OFF_T/OFF_D/OFF_B
//  k_scatter  : one pass; LDS cursors; emits t-sorted entries, d-sorted refs, Y slots
//  k_phaseA   : per t-bucket GEMM  xt = x[b,j] @ Tw[t]   (Tw in LDS) -> XT[tpos][64]
//  k_phaseB   : per d-bucket GEMM  y = xt @ Dw[d] (Dw in LDS) -> Y[dstpos][128]
//  k_reduce   : XC[b,i,:] = sum of its contiguous Y rows
//  k_recur    : h = sigmoid(XC[b,i] + h@Wh); 2 waves/block, wave owns 64 cols,
//               Wh column in VGPRs as 64 half2, h in LDS as f16 (256 B, dbuf),
//               v_dot2_f32_f16 -> 8 operands per ds_read_b128, ONE barrier/step.
//
// ws requirement: ~104.3 MB for the atomic-free path (guarded; fallback = atomicAdd XC).

#define B_ 16
#define S_ 128
#define D_ 64
#define K_ 64
#define H_ 128
#define NS 97
#define MAXE 132096  // B * S*(S+1)/2  (upper bound on valid triples)

// u32/f32-index offsets into ws
#define XC_OFF 0                  // f32 [2048][128]
#define BH_T   262144             // u32 [97][256]  per-(bin,block) hist -> bases
#define BH_D   (BH_T + 24832)     // u32 [97][256]
#define CNT_T  (BH_D + 24832)     // u32 [97]
#define CNT_D  (CNT_T + 97)       // u32 [97]
#define CNT_B  (CNT_D + 97)       // u32 [2048]
#define OFF_T  (CNT_B + 2048)     // u32 [98] (last = total)
#define OFF_D  (OFF_T + 98)       // u32 [98]
#define OFF_B  (OFF_D + 98)       // u32 [2049]
#define ENT_T  316296             // u32 [MAXE] packed: b|i<<4|j<<11|t<<18|d<<25 (16B-aligned)
#define ENT_DX (ENT_T + MAXE)     // u32 [MAXE] xt-row index (t-sorted pos)
#define ENT_DP (ENT_DX + MAXE)    // u32 [MAXE] Y-row (dst-sorted pos) [or dst in fallback]
#define XT_OFF (ENT_DP + MAXE)    // f32 [MAXE][64]
#define Y_OFF  (XT_OFF + MAXE * 64)            // f32 [MAXE][128]
#define NEED_BYTES ((size_t)(Y_OFF + (size_t)MAXE * 128) * 4)

typedef _Float16 h2_t __attribute__((ext_vector_type(2)));

#if __has_builtin(__builtin_amdgcn_fdot2)
#define FDOT2(a, b, c) __builtin_amdgcn_fdot2((a), (b), (c), false)
#else
#define FDOT2(a, b, c) ((c) + (float)(a)[0] * (float)(b)[0] + (float)(a)[1] * (float)(b)[1])
#endif

// ---- binning: 256 blocks x 1024 elements (8 full (b,i) rows per block) ----

__global__ __launch_bounds__(256) void k_hist1(const int* __restrict__ tc,
                                               const int* __restrict__ dc,
                                               const int* __restrict__ mk,
                                               unsigned* wsi) {
    __shared__ unsigned ht[NS], hd[NS], hb[8];
    int tid = threadIdx.x, blk = blockIdx.x;
    if (tid < NS) { ht[tid] = 0; hd[tid] = 0; }
    if (tid < 8) hb[tid] = 0;
    __syncthreads();
    int base = blk * 1024;
    #pragma unroll
    for (int u = 0; u < 4; u++) {
        int idx = base + tid + u * 256;
        int i = (idx >> 7) & 127, j = idx & 127;
        if (j <= i && mk[idx] != 0) {
            atomicAdd(&ht[tc[idx]], 1u);
            atomicAdd(&hd[dc[idx]], 1u);
            atomicAdd(&hb[(idx >> 7) & 7], 1u);
        }
    }
    __syncthreads();
    if (tid < NS) {
        wsi[BH_T + tid * 256 + blk] = ht[tid];
        wsi[BH_D + tid * 256 + blk] = hd[tid];
    }
    if (tid < 8) wsi[CNT_B + blk * 8 + tid] = hb[tid];
}

template <int CH>
__device__ unsigned scan_region(unsigned* in, unsigned* out, int L, unsigned* s) {
    int tid = threadIdx.x;
    unsigned loc[CH], sum = 0;
    #pragma unroll
    for (int k = 0; k < CH; k++) {
        int idx = tid * CH + k;
        loc[k] = (idx < L) ? in[idx] : 0u;
        sum += loc[k];
    }
    s[tid] = sum;
    __syncthreads();
    for (int o = 1; o < 1024; o <<= 1) {
        unsigned a = (tid >= o) ? s[tid - o] : 0u;
        __syncthreads();
        s[tid] += a;
        __syncthreads();
    }
    unsigned total = s[1023];
    unsigned run = s[tid] - sum;
    __syncthreads();
    #pragma unroll
    for (int k = 0; k < CH; k++) {
        int idx = tid * CH + k;
        if (idx < L) { out[idx] = run; run += loc[k]; }
    }
    __syncthreads();
    return total;
}

__global__ __launch_bounds__(1024) void k_scan_all(unsigned* wsi) {
    __shared__ unsigned s[1024];
    int tid = threadIdx.x;

    unsigned totT = scan_region<25>(wsi + BH_T, wsi + BH_T, NS * 256, s);
    if (tid < NS) {
        unsigned b0 = wsi[BH_T + tid * 256];
        unsigned b1 = (tid < NS - 1) ? wsi[BH_T + (tid + 1) * 256] : totT;
        wsi[OFF_T + tid] = b0;
        wsi[CNT_T + tid] = b1 - b0;
    }
    if (tid == 0) wsi[OFF_T + NS] = totT;
    __syncthreads();

    unsigned totD = scan_region<25>(wsi + BH_D, wsi + BH_D, NS * 256, s);
    if (tid < NS) {
        unsigned b0 = wsi[BH_D + tid * 256];
        unsigned b1 = (tid < NS - 1) ? wsi[BH_D + (tid + 1) * 256] : totD;
        wsi[OFF_D + tid] = b0;
        wsi[CNT_D + tid] = b1 - b0;
    }
    if (tid == 0) wsi[OFF_D + NS] = totD;
    __syncthreads();

    unsigned totB = scan_region<2>(wsi + CNT_B, wsi + OFF_B, 2048, s);
    if (tid == 0) wsi[OFF_B + 2048] = totB;
}

__global__ __launch_bounds__(256) void k_scatter(const int* __restrict__ tc,
                                                 const int* __restrict__ dc,
                                                 const int* __restrict__ mk,
                                                 unsigned* wsi, int useY) {
    __shared__ unsigned ct[NS], cd[NS], cb[8];
    int tid = threadIdx.x, blk = blockIdx.x;
    if (tid < NS) {
        ct[tid] = wsi[BH_T + tid * 256 + blk];
        cd[tid] = wsi[BH_D + tid * 256 + blk];
    }
    if (tid < 8) cb[tid] = wsi[OFF_B + blk * 8 + tid];
    __syncthreads();
    int base = blk * 1024;
    #pragma unroll
    for (int u = 0; u < 4; u++) {
        int idx = base + tid + u * 256;
        int i = (idx >> 7) & 127, j = idx & 127, b = idx >> 14;
        if (j <= i && mk[idx] != 0) {
            unsigned t = (unsigned)tc[idx], d = (unsigned)dc[idx];
            unsigned tpos = atomicAdd(&ct[t], 1u);
            wsi[ENT_T + tpos] = (unsigned)b | ((unsigned)i << 4) | ((unsigned)j << 11)
                              | (t << 18) | (d << 25);
            unsigned dpos = atomicAdd(&cd[d], 1u);
            unsigned yp = useY ? atomicAdd(&cb[(idx >> 7) & 7], 1u) : (unsigned)(idx >> 7);
            wsi[ENT_DX + dpos] = tpos;
            wsi[ENT_DP + dpos] = yp;
        }
    }
}

// phase A: xt[entry][kk] = sum_dd x[b,j][dd] * Tw[t][dd][kk]
__global__ __launch_bounds__(256) void k_phaseA(const float* __restrict__ x,
                                                const float* __restrict__ tw,
                                                unsigned* wsi, float* wsf) {
    int t = blockIdx.x, c = blockIdx.y;
    int rows = (int)wsi[CNT_T + t] - c * 128;
    if (rows <= 0) return;
    if (rows > 128) rows = 128;
    unsigned base = wsi[OFF_T + t] + c * 128;

    __shared__ float stw[4096];     // Tw[t] row-major [dd][kk]
    __shared__ float sx[8192];      // x rows, XOR-swizzled in 4-float units
    __shared__ unsigned ent[128];
    int tid = threadIdx.x;

    const float4* twg = (const float4*)(tw + t * 4096);
    float4* stw4 = (float4*)stw;
    #pragma unroll
    for (int q = 0; q < 4; q++) stw4[q * 256 + tid] = twg[q * 256 + tid];
    if (tid < 128) ent[tid] = (tid < rows) ? wsi[ENT_T + base + tid] : 0u;
    __syncthreads();

    int lane16 = tid & 15, rquot = tid >> 4;
    #pragma unroll
    for (int p = 0; p < 8; p++) {
        int r = p * 16 + rquot;
        float4 v = make_float4(0.f, 0.f, 0.f, 0.f);
        if (r < rows) {
            unsigned e = ent[r];
            int b = e & 15, j = (e >> 11) & 127;
            v = *(const float4*)(x + (b * S_ + j) * D_ + lane16 * 4);
        }
        int col4 = lane16 ^ (r & 15);
        float* dst = &sx[r * 64 + col4 * 4];
        dst[0] = v.x; dst[1] = v.y; dst[2] = v.z; dst[3] = v.w;
    }
    __syncthreads();

    int rgrp = tid & 15, cgrp = tid >> 4;   // 8 rows (rgrp+16i) x 4 cols (cgrp*4..)
    float4 acc[8];
    #pragma unroll
    for (int i = 0; i < 8; i++) acc[i] = make_float4(0.f, 0.f, 0.f, 0.f);
    #pragma unroll 4
    for (int dd = 0; dd < 64; dd++) {
        float4 w = stw4[dd * 16 + cgrp];
        int s_idx = (((dd >> 2) ^ rgrp) << 2) + (dd & 3);
        #pragma unroll
        for (int i = 0; i < 8; i++) {
            float a = sx[(rgrp + 16 * i) * 64 + s_idx];
            acc[i].x += a * w.x; acc[i].y += a * w.y;
            acc[i].z += a * w.z; acc[i].w += a * w.w;
        }
    }
    float* XT = wsf + XT_OFF;
    #pragma unroll
    for (int i = 0; i < 8; i++) {
        int r = rgrp + 16 * i;
        if (r < rows) *(float4*)(XT + (size_t)(base + r) * 64 + cgrp * 4) = acc[i];
    }
}

// phase B: y[hh] = sum_kk xt[entry][kk] * Dw[d][kk][hh]; write to Y[dstpos] (or atomic XC)
__global__ __launch_bounds__(256) void k_phaseB(const float* __restrict__ dw,
                                                unsigned* wsi, float* wsf, int useY) {
    int d = blockIdx.x, c = blockIdx.y;
    int rows = (int)wsi[CNT_D + d] - c * 128;
    if (rows <= 0) return;
    if (rows > 128) rows = 128;
    unsigned base = wsi[OFF_D + d] + c * 128;

    __shared__ float sdw[8192];     // Dw[d] row-major [kk][hh]
    __shared__ float sx[8192];      // xt rows, swizzled
    __shared__ unsigned entx[128];
    __shared__ unsigned entp[128];
    int tid = threadIdx.x;

    const float4* dwg = (const float4*)(dw + (size_t)d * 8192);
    float4* sdw4 = (float4*)sdw;
    #pragma unroll
    for (int q = 0; q < 8; q++) sdw4[q * 256 + tid] = dwg[q * 256 + tid];
    if (tid < 128) {
        entx[tid] = (tid < rows) ? wsi[ENT_DX + base + tid] : 0u;
        entp[tid] = (tid < rows) ? wsi[ENT_DP + base + tid] : 0u;
    }
    __syncthreads();

    const float* XT = wsf + XT_OFF;
    int lane16 = tid & 15, rquot = tid >> 4;
    #pragma unroll
    for (int p = 0; p < 8; p++) {
        int r = p * 16 + rquot;
        float4 v = make_float4(0.f, 0.f, 0.f, 0.f);
        if (r < rows) {
            unsigned pos = entx[r];
            v = *(const float4*)(XT + (size_t)pos * 64 + lane16 * 4);
        }
        int col4 = lane16 ^ (r & 15);
        float* dst2 = &sx[r * 64 + col4 * 4];
        dst2[0] = v.x; dst2[1] = v.y; dst2[2] = v.z; dst2[3] = v.w;
    }
    __syncthreads();

    int rgrp = tid & 15, cgrp = tid >> 4;   // 8 rows x 8 cols (cgrp*8..)
    float4 a0[8], a1[8];
    #pragma unroll
    for (int i = 0; i < 8; i++) {
        a0[i] = make_float4(0.f, 0.f, 0.f, 0.f);
        a1[i] = make_float4(0.f, 0.f, 0.f, 0.f);
    }
    #pragma unroll 2
    for (int kk = 0; kk < 64; kk++) {
        float4 w0 = sdw4[kk * 32 + cgrp * 2];
        float4 w1 = sdw4[kk * 32 + cgrp * 2 + 1];
        int s_idx = (((kk >> 2) ^ rgrp) << 2) + (kk & 3);
        #pragma unroll
        for (int i = 0; i < 8; i++) {
            float a = sx[(rgrp + 16 * i) * 64 + s_idx];
            a0[i].x += a * w0.x; a0[i].y += a * w0.y; a0[i].z += a * w0.z; a0[i].w += a * w0.w;
            a1[i].x += a * w1.x; a1[i].y += a * w1.y; a1[i].z += a * w1.z; a1[i].w += a * w1.w;
        }
    }
    if (useY) {
        float* Y = wsf + Y_OFF;
        #pragma unroll
        for (int i = 0; i < 8; i++) {
            int r = rgrp + 16 * i;
            if (r < rows) {
                float* p = Y + (size_t)entp[r] * 128 + cgrp * 8;
                *(float4*)p = a0[i];
                *(float4*)(p + 4) = a1[i];
            }
        }
    } else {
        float* XC = wsf + XC_OFF;
        #pragma unroll
        for (int i = 0; i < 8; i++) {
            int r = rgrp + 16 * i;
            if (r < rows) {
                float* p = XC + (size_t)entp[r] * 128 + cgrp * 8;
                atomicAdd(p + 0, a0[i].x); atomicAdd(p + 1, a0[i].y);
                atomicAdd(p + 2, a0[i].z); atomicAdd(p + 3, a0[i].w);
                atomicAdd(p + 4, a1[i].x); atomicAdd(p + 5, a1[i].y);
                atomicAdd(p + 6, a1[i].z); atomicAdd(p + 7, a1[i].w);
            }
        }
    }
}

// XC[b,i,:] = sum of this (b,i)'s contiguous Y rows
__global__ __launch_bounds__(128) void k_reduce(unsigned* wsi, float* wsf) {
    int bi = blockIdx.x, tid = threadIdx.x;
    unsigned n = wsi[CNT_B + bi], off = wsi[OFF_B + bi];
    const float* Yp = wsf + Y_OFF + (size_t)off * 128 + tid;
    float a0 = 0.f, a1 = 0.f, a2 = 0.f, a3 = 0.f;
    unsigned e = 0;
    for (; e + 4 <= n; e += 4) {
        a0 += Yp[(size_t)e * 128];
        a1 += Yp[(size_t)(e + 1) * 128];
        a2 += Yp[(size_t)(e + 2) * 128];
        a3 += Yp[(size_t)(e + 3) * 128];
    }
    for (; e < n; e++) a0 += Yp[(size_t)e * 128];
    wsf[XC_OFF + (size_t)bi * 128 + tid] = (a0 + a1) + (a2 + a3);
}

// recurrence: h_new = sigmoid(XC[b,i] + h @ Wh); one block (128 thr = 2 waves) per b.
// Wave wv covers cols wv*64..wv*64+63 (lane = col offset), FULL K per lane.
// Wh column lives in VGPRs as 64 half2 (w2[m] = {Wh[2m][col], Wh[2m+1][col]}).
// h stored in LDS as f16 (128 halves = 256 B), double-buffered -> 1 barrier/step.
// Dot: 16 broadcast ds_read_b128 (8 operands each) + 64 v_dot2_f32_f16.
__global__ __launch_bounds__(128) void k_recur(const float* __restrict__ hw,
                                               const float* __restrict__ wsf,
                                               float* __restrict__ out) {
    int b = blockIdx.x;
    __shared__ float swh[16384];        // staging for weight transpose (used once)
    __shared__ h2_t h16[2][64];         // [buf][64 half2] = 128 halves
    int tid = threadIdx.x;
    int lane = tid & 63, wv = tid >> 6;
    int col = wv * 64 + lane;

    const float4* hwg = (const float4*)hw;
    float4* swh4 = (float4*)swh;
    #pragma unroll
    for (int q = 0; q < 32; q++) swh4[q * 128 + tid] = hwg[q * 128 + tid];
    if (tid < 64) { h16[0][tid] = (h2_t)(_Float16)0.f; }
    __syncthreads();

    h2_t w2[64];
    #pragma unroll
    for (int m = 0; m < 64; m++) {
        h2_t p;
        p[0] = (_Float16)swh[(2 * m) * 128 + col];
        p[1] = (_Float16)swh[(2 * m + 1) * 128 + col];
        w2[m] = p;
    }

    const float* XC = wsf + XC_OFF + (size_t)b * 128 * 128;
    float xc_next = XC[col];            // row 0 prefetch
    int cur = 0;
    float val = 0.f;
    for (int i = 0; i < 128; i++) {
        float xc = xc_next;
        if (i < 127) xc_next = XC[(i + 1) * 128 + col];
        const float4* hb = (const float4*)&h16[cur][0];
        float acc0 = 0.f, acc1 = 0.f, acc2 = 0.f, acc3 = 0.f;
        #pragma unroll
        for (int q = 0; q < 16; q++) {   // 16 broadcast b128 reads of h16
            union { float4 f4; h2_t h2[4]; } u;
            u.f4 = hb[q];
            acc0 = FDOT2(u.h2[0], w2[4 * q + 0], acc0);
            acc1 = FDOT2(u.h2[1], w2[4 * q + 1], acc1);
            acc2 = FDOT2(u.h2[2], w2[4 * q + 2], acc2);
            acc3 = FDOT2(u.h2[3], w2[4 * q + 3], acc3);
        }
        val = xc + (acc0 + acc1) + (acc2 + acc3);
        val = 1.f / (1.f + __expf(-val));
        // publish h as f16 pair element (col -> h16[cur^1][col>>1][col&1])
        ((_Float16*)&h16[cur ^ 1][0])[col] = (_Float16)val;
        out[(size_t)(b * 128 + i) * 128 + col] = val;
        cur ^= 1;
        __syncthreads();
    }
    out[(size_t)B_ * S_ * H_ + b * 128 + col] = val;
}

extern "C" void kernel_launch(void* const* d_in, const int* in_sizes, int n_in,
                              void* d_out, int out_size, void* d_ws, size_t ws_size,
                              hipStream_t stream) {
    const float* x  = (const float*)d_in[0];
    const int*   tc = (const int*)d_in[1];
    const int*   dc = (const int*)d_in[2];
    const int*   mk = (const int*)d_in[3];   // bool masks pushed as int32
    const float* tw = (const float*)d_in[4];
    const float* dw = (const float*)d_in[5];
    const float* hw = (const float*)d_in[6];
    float*    out = (float*)d_out;
    float*    wsf = (float*)d_ws;
    unsigned* wsi = (unsigned*)d_ws;
    char*     wsb = (char*)d_ws;

    int useY = (ws_size >= NEED_BYTES) ? 1 : 0;
    if (!useY)  // fallback path accumulates into XC with atomics -> needs zeroed XC
        hipMemsetAsync(wsb, 0, (size_t)262144 * 4, stream);

    k_hist1<<<dim3(256), dim3(256), 0, stream>>>(tc, dc, mk, wsi);
    k_scan_all<<<dim3(1), dim3(1024), 0, stream>>>(wsi);
    k_scatter<<<dim3(256), dim3(256), 0, stream>>>(tc, dc, mk, wsi, useY);
    k_phaseA<<<dim3(NS, 16), dim3(256), 0, stream>>>(x, tw, wsi, wsf);
    k_phaseB<<<dim3(NS, 16), dim3(256), 0, stream>>>(dw, wsi, wsf, useY);
    if (useY) k_reduce<<<dim3(2048), dim3(128), 0, stream>>>(wsi, wsf);
    k_recur<<<dim3(16), dim3(128), 0, stream>>>(hw, wsf, out);
}

// Round 8
// 164.547 us; speedup vs baseline: 1.2012x; 1.0041x over previous
//
#include <hip/hip_runtime.h>
#include <math.h>

// STRNN: B=16, S=128, D=64, K=64, H=128, NSLOT+1=97 slots.
//
// Pipeline (all f32 except recurrence dot in f16x2->f32 dot2):
//  k_hist1    : per-block LDS histograms of t-slot / d-slot / per-(b,i) counts
//  k_scan_all : exclusive scans -> per-(bin,block) bases + OFF_T/OFF_D/OFF_B
//  k_scatter  : one pass; LDS cursors; emits t-sorted entries, d-sorted refs, Y slots
//  k_phaseA   : per t-bucket GEMM  xt = x[b,j] @ Tw[t]   (Tw in LDS) -> XT[tpos][64]
//  k_phaseB   : per d-bucket GEMM  y = xt @ Dw[d] (Dw in LDS) -> Y[dstpos][128]
//  k_reduce   : XC[b,i,:] = sum of its contiguous Y rows
//  k_recur    : h = sigmoid(XC[b,i] + h@Wh); SINGLE WAVE per batch -> NO barrier.
//               Lane owns cols 2l,2l+1; both Wh columns in VGPRs as 128 half2;
//               h in 512B LDS as f16, dbuf; v_dot2_f32_f16 inner product.
//
// ws requirement: ~104.3 MB for the atomic-free path (guarded; fallback = atomicAdd XC).

#define B_ 16
#define S_ 128
#define D_ 64
#define K_ 64
#define H_ 128
#define NS 97
#define MAXE 132096  // B * S*(S+1)/2  (upper bound on valid triples)

// u32/f32-index offsets into ws
#define XC_OFF 0                  // f32 [2048][128]
#define BH_T   262144             // u32 [97][256]  per-(bin,block) hist -> bases
#define BH_D   (BH_T + 24832)     // u32 [97][256]
#define CNT_T  (BH_D + 24832)     // u32 [97]
#define CNT_D  (CNT_T + 97)       // u32 [97]
#define CNT_B  (CNT_D + 97)       // u32 [2048]
#define OFF_T  (CNT_B + 2048)     // u32 [98] (last = total)
#define OFF_D  (OFF_T + 98)       // u32 [98]
#define OFF_B  (OFF_D + 98)       // u32 [2049]
#define ENT_T  316296             // u32 [MAXE] packed: b|i<<4|j<<11|t<<18|d<<25 (16B-aligned)
#define ENT_DX (ENT_T + MAXE)     // u32 [MAXE] xt-row index (t-sorted pos)
#define ENT_DP (ENT_DX + MAXE)    // u32 [MAXE] Y-row (dst-sorted pos) [or dst in fallback]
#define XT_OFF (ENT_DP + MAXE)    // f32 [MAXE][64]
#define Y_OFF  (XT_OFF + MAXE * 64)            // f32 [MAXE][128]
#define NEED_BYTES ((size_t)(Y_OFF + (size_t)MAXE * 128) * 4)

typedef _Float16 h2_t __attribute__((ext_vector_type(2)));

#if __has_builtin(__builtin_amdgcn_fdot2)
#define FDOT2(a, b, c) __builtin_amdgcn_fdot2((a), (b), (c), false)
#else
#define FDOT2(a, b, c) ((c) + (float)(a)[0] * (float)(b)[0] + (float)(a)[1] * (float)(b)[1])
#endif

// ---- binning: 256 blocks x 1024 elements (8 full (b,i) rows per block) ----

__global__ __launch_bounds__(256) void k_hist1(const int* __restrict__ tc,
                                               const int* __restrict__ dc,
                                               const int* __restrict__ mk,
                                               unsigned* wsi) {
    __shared__ unsigned ht[NS], hd[NS], hb[8];
    int tid = threadIdx.x, blk = blockIdx.x;
    if (tid < NS) { ht[tid] = 0; hd[tid] = 0; }
    if (tid < 8) hb[tid] = 0;
    __syncthreads();
    int base = blk * 1024;
    #pragma unroll
    for (int u = 0; u < 4; u++) {
        int idx = base + tid + u * 256;
        int i = (idx >> 7) & 127, j = idx & 127;
        if (j <= i && mk[idx] != 0) {
            atomicAdd(&ht[tc[idx]], 1u);
            atomicAdd(&hd[dc[idx]], 1u);
            atomicAdd(&hb[(idx >> 7) & 7], 1u);
        }
    }
    __syncthreads();
    if (tid < NS) {
        wsi[BH_T + tid * 256 + blk] = ht[tid];
        wsi[BH_D + tid * 256 + blk] = hd[tid];
    }
    if (tid < 8) wsi[CNT_B + blk * 8 + tid] = hb[tid];
}

template <int CH>
__device__ unsigned scan_region(unsigned* in, unsigned* out, int L, unsigned* s) {
    int tid = threadIdx.x;
    unsigned loc[CH], sum = 0;
    #pragma unroll
    for (int k = 0; k < CH; k++) {
        int idx = tid * CH + k;
        loc[k] = (idx < L) ? in[idx] : 0u;
        sum += loc[k];
    }
    s[tid] = sum;
    __syncthreads();
    for (int o = 1; o < 1024; o <<= 1) {
        unsigned a = (tid >= o) ? s[tid - o] : 0u;
        __syncthreads();
        s[tid] += a;
        __syncthreads();
    }
    unsigned total = s[1023];
    unsigned run = s[tid] - sum;
    __syncthreads();
    #pragma unroll
    for (int k = 0; k < CH; k++) {
        int idx = tid * CH + k;
        if (idx < L) { out[idx] = run; run += loc[k]; }
    }
    __syncthreads();
    return total;
}

__global__ __launch_bounds__(1024) void k_scan_all(unsigned* wsi) {
    __shared__ unsigned s[1024];
    int tid = threadIdx.x;

    unsigned totT = scan_region<25>(wsi + BH_T, wsi + BH_T, NS * 256, s);
    if (tid < NS) {
        unsigned b0 = wsi[BH_T + tid * 256];
        unsigned b1 = (tid < NS - 1) ? wsi[BH_T + (tid + 1) * 256] : totT;
        wsi[OFF_T + tid] = b0;
        wsi[CNT_T + tid] = b1 - b0;
    }
    if (tid == 0) wsi[OFF_T + NS] = totT;
    __syncthreads();

    unsigned totD = scan_region<25>(wsi + BH_D, wsi + BH_D, NS * 256, s);
    if (tid < NS) {
        unsigned b0 = wsi[BH_D + tid * 256];
        unsigned b1 = (tid < NS - 1) ? wsi[BH_D + (tid + 1) * 256] : totD;
        wsi[OFF_D + tid] = b0;
        wsi[CNT_D + tid] = b1 - b0;
    }
    if (tid == 0) wsi[OFF_D + NS] = totD;
    __syncthreads();

    unsigned totB = scan_region<2>(wsi + CNT_B, wsi + OFF_B, 2048, s);
    if (tid == 0) wsi[OFF_B + 2048] = totB;
}

__global__ __launch_bounds__(256) void k_scatter(const int* __restrict__ tc,
                                                 const int* __restrict__ dc,
                                                 const int* __restrict__ mk,
                                                 unsigned* wsi, int useY) {
    __shared__ unsigned ct[NS], cd[NS], cb[8];
    int tid = threadIdx.x, blk = blockIdx.x;
    if (tid < NS) {
        ct[tid] = wsi[BH_T + tid * 256 + blk];
        cd[tid] = wsi[BH_D + tid * 256 + blk];
    }
    if (tid < 8) cb[tid] = wsi[OFF_B + blk * 8 + tid];
    __syncthreads();
    int base = blk * 1024;
    #pragma unroll
    for (int u = 0; u < 4; u++) {
        int idx = base + tid + u * 256;
        int i = (idx >> 7) & 127, j = idx & 127, b = idx >> 14;
        if (j <= i && mk[idx] != 0) {
            unsigned t = (unsigned)tc[idx], d = (unsigned)dc[idx];
            unsigned tpos = atomicAdd(&ct[t], 1u);
            wsi[ENT_T + tpos] = (unsigned)b | ((unsigned)i << 4) | ((unsigned)j << 11)
                              | (t << 18) | (d << 25);
            unsigned dpos = atomicAdd(&cd[d], 1u);
            unsigned yp = useY ? atomicAdd(&cb[(idx >> 7) & 7], 1u) : (unsigned)(idx >> 7);
            wsi[ENT_DX + dpos] = tpos;
            wsi[ENT_DP + dpos] = yp;
        }
    }
}

// phase A: xt[entry][kk] = sum_dd x[b,j][dd] * Tw[t][dd][kk]
__global__ __launch_bounds__(256) void k_phaseA(const float* __restrict__ x,
                                                const float* __restrict__ tw,
                                                unsigned* wsi, float* wsf) {
    int t = blockIdx.x, c = blockIdx.y;
    int rows = (int)wsi[CNT_T + t] - c * 128;
    if (rows <= 0) return;
    if (rows > 128) rows = 128;
    unsigned base = wsi[OFF_T + t] + c * 128;

    __shared__ float stw[4096];     // Tw[t] row-major [dd][kk]
    __shared__ float sx[8192];      // x rows, XOR-swizzled in 4-float units
    __shared__ unsigned ent[128];
    int tid = threadIdx.x;

    const float4* twg = (const float4*)(tw + t * 4096);
    float4* stw4 = (float4*)stw;
    #pragma unroll
    for (int q = 0; q < 4; q++) stw4[q * 256 + tid] = twg[q * 256 + tid];
    if (tid < 128) ent[tid] = (tid < rows) ? wsi[ENT_T + base + tid] : 0u;
    __syncthreads();

    int lane16 = tid & 15, rquot = tid >> 4;
    #pragma unroll
    for (int p = 0; p < 8; p++) {
        int r = p * 16 + rquot;
        float4 v = make_float4(0.f, 0.f, 0.f, 0.f);
        if (r < rows) {
            unsigned e = ent[r];
            int b = e & 15, j = (e >> 11) & 127;
            v = *(const float4*)(x + (b * S_ + j) * D_ + lane16 * 4);
        }
        int col4 = lane16 ^ (r & 15);
        float* dst = &sx[r * 64 + col4 * 4];
        dst[0] = v.x; dst[1] = v.y; dst[2] = v.z; dst[3] = v.w;
    }
    __syncthreads();

    int rgrp = tid & 15, cgrp = tid >> 4;   // 8 rows (rgrp+16i) x 4 cols (cgrp*4..)
    float4 acc[8];
    #pragma unroll
    for (int i = 0; i < 8; i++) acc[i] = make_float4(0.f, 0.f, 0.f, 0.f);
    #pragma unroll 4
    for (int dd = 0; dd < 64; dd++) {
        float4 w = stw4[dd * 16 + cgrp];
        int s_idx = (((dd >> 2) ^ rgrp) << 2) + (dd & 3);
        #pragma unroll
        for (int i = 0; i < 8; i++) {
            float a = sx[(rgrp + 16 * i) * 64 + s_idx];
            acc[i].x += a * w.x; acc[i].y += a * w.y;
            acc[i].z += a * w.z; acc[i].w += a * w.w;
        }
    }
    float* XT = wsf + XT_OFF;
    #pragma unroll
    for (int i = 0; i < 8; i++) {
        int r = rgrp + 16 * i;
        if (r < rows) *(float4*)(XT + (size_t)(base + r) * 64 + cgrp * 4) = acc[i];
    }
}

// phase B: y[hh] = sum_kk xt[entry][kk] * Dw[d][kk][hh]; write to Y[dstpos] (or atomic XC)
__global__ __launch_bounds__(256) void k_phaseB(const float* __restrict__ dw,
                                                unsigned* wsi, float* wsf, int useY) {
    int d = blockIdx.x, c = blockIdx.y;
    int rows = (int)wsi[CNT_D + d] - c * 128;
    if (rows <= 0) return;
    if (rows > 128) rows = 128;
    unsigned base = wsi[OFF_D + d] + c * 128;

    __shared__ float sdw[8192];     // Dw[d] row-major [kk][hh]
    __shared__ float sx[8192];      // xt rows, swizzled
    __shared__ unsigned entx[128];
    __shared__ unsigned entp[128];
    int tid = threadIdx.x;

    const float4* dwg = (const float4*)(dw + (size_t)d * 8192);
    float4* sdw4 = (float4*)sdw;
    #pragma unroll
    for (int q = 0; q < 8; q++) sdw4[q * 256 + tid] = dwg[q * 256 + tid];
    if (tid < 128) {
        entx[tid] = (tid < rows) ? wsi[ENT_DX + base + tid] : 0u;
        entp[tid] = (tid < rows) ? wsi[ENT_DP + base + tid] : 0u;
    }
    __syncthreads();

    const float* XT = wsf + XT_OFF;
    int lane16 = tid & 15, rquot = tid >> 4;
    #pragma unroll
    for (int p = 0; p < 8; p++) {
        int r = p * 16 + rquot;
        float4 v = make_float4(0.f, 0.f, 0.f, 0.f);
        if (r < rows) {
            unsigned pos = entx[r];
            v = *(const float4*)(XT + (size_t)pos * 64 + lane16 * 4);
        }
        int col4 = lane16 ^ (r & 15);
        float* dst2 = &sx[r * 64 + col4 * 4];
        dst2[0] = v.x; dst2[1] = v.y; dst2[2] = v.z; dst2[3] = v.w;
    }
    __syncthreads();

    int rgrp = tid & 15, cgrp = tid >> 4;   // 8 rows x 8 cols (cgrp*8..)
    float4 a0[8], a1[8];
    #pragma unroll
    for (int i = 0; i < 8; i++) {
        a0[i] = make_float4(0.f, 0.f, 0.f, 0.f);
        a1[i] = make_float4(0.f, 0.f, 0.f, 0.f);
    }
    #pragma unroll 2
    for (int kk = 0; kk < 64; kk++) {
        float4 w0 = sdw4[kk * 32 + cgrp * 2];
        float4 w1 = sdw4[kk * 32 + cgrp * 2 + 1];
        int s_idx = (((kk >> 2) ^ rgrp) << 2) + (kk & 3);
        #pragma unroll
        for (int i = 0; i < 8; i++) {
            float a = sx[(rgrp + 16 * i) * 64 + s_idx];
            a0[i].x += a * w0.x; a0[i].y += a * w0.y; a0[i].z += a * w0.z; a0[i].w += a * w0.w;
            a1[i].x += a * w1.x; a1[i].y += a * w1.y; a1[i].z += a * w1.z; a1[i].w += a * w1.w;
        }
    }
    if (useY) {
        float* Y = wsf + Y_OFF;
        #pragma unroll
        for (int i = 0; i < 8; i++) {
            int r = rgrp + 16 * i;
            if (r < rows) {
                float* p = Y + (size_t)entp[r] * 128 + cgrp * 8;
                *(float4*)p = a0[i];
                *(float4*)(p + 4) = a1[i];
            }
        }
    } else {
        float* XC = wsf + XC_OFF;
        #pragma unroll
        for (int i = 0; i < 8; i++) {
            int r = rgrp + 16 * i;
            if (r < rows) {
                float* p = XC + (size_t)entp[r] * 128 + cgrp * 8;
                atomicAdd(p + 0, a0[i].x); atomicAdd(p + 1, a0[i].y);
                atomicAdd(p + 2, a0[i].z); atomicAdd(p + 3, a0[i].w);
                atomicAdd(p + 4, a1[i].x); atomicAdd(p + 5, a1[i].y);
                atomicAdd(p + 6, a1[i].z); atomicAdd(p + 7, a1[i].w);
            }
        }
    }
}

// XC[b,i,:] = sum of this (b,i)'s contiguous Y rows
__global__ __launch_bounds__(128) void k_reduce(unsigned* wsi, float* wsf) {
    int bi = blockIdx.x, tid = threadIdx.x;
    unsigned n = wsi[CNT_B + bi], off = wsi[OFF_B + bi];
    const float* Yp = wsf + Y_OFF + (size_t)off * 128 + tid;
    float a0 = 0.f, a1 = 0.f, a2 = 0.f, a3 = 0.f;
    unsigned e = 0;
    for (; e + 4 <= n; e += 4) {
        a0 += Yp[(size_t)e * 128];
        a1 += Yp[(size_t)(e + 1) * 128];
        a2 += Yp[(size_t)(e + 2) * 128];
        a3 += Yp[(size_t)(e + 3) * 128];
    }
    for (; e < n; e++) a0 += Yp[(size_t)e * 128];
    wsf[XC_OFF + (size_t)bi * 128 + tid] = (a0 + a1) + (a2 + a3);
}

// recurrence: h_new = sigmoid(XC[b,i] + h @ Wh); ONE WAVE (64 thr) per batch b.
// Lane owns cols c0=2*lane, c1=2*lane+1; weight columns in VGPRs as 128 half2
// (w2a/w2b[m] = {Wh[2m][c],Wh[2m+1][c]}), loaded via coalesced float2 from global.
// h lives in 512B LDS as f16 (dbuf). NO s_barrier anywhere: single-wave lockstep +
// compiler lgkmcnt ordering is sufficient.
__global__ __launch_bounds__(64) void k_recur(const float* __restrict__ hw,
                                              const float* __restrict__ wsf,
                                              float* __restrict__ out) {
    int b = blockIdx.x;
    __shared__ h2_t h16[2][64];         // [buf][64 half2] = 128 halves
    int lane = threadIdx.x;             // 0..63
    int c0 = 2 * lane;

    h2_t w2a[64], w2b[64];
    #pragma unroll
    for (int m = 0; m < 64; m++) {
        float2 e = *(const float2*)&hw[(2 * m) * 128 + c0];       // row 2m, cols c0,c0+1
        float2 o = *(const float2*)&hw[(2 * m + 1) * 128 + c0];   // row 2m+1
        h2_t p, q2;
        p[0] = (_Float16)e.x;  p[1] = (_Float16)o.x;
        q2[0] = (_Float16)e.y; q2[1] = (_Float16)o.y;
        w2a[m] = p; w2b[m] = q2;
    }
    h16[0][lane] = (h2_t)(_Float16)0.f;

    const float* XC = wsf + XC_OFF + (size_t)b * 128 * 128;
    float2 xc_next = *(const float2*)&XC[c0];   // row 0 prefetch
    int cur = 0;
    float2 val = make_float2(0.f, 0.f);
    for (int i = 0; i < 128; i++) {
        float2 xc = xc_next;
        if (i < 127) xc_next = *(const float2*)&XC[(i + 1) * 128 + c0];
        const float4* hb = (const float4*)&h16[cur][0];
        float a0 = 0.f, a1 = 0.f, b0 = 0.f, b1 = 0.f;
        #pragma unroll
        for (int q = 0; q < 16; q++) {   // 16 broadcast b128 reads of h16
            union { float4 f4; h2_t h2[4]; } u;
            u.f4 = hb[q];
            a0 = FDOT2(u.h2[0], w2a[4 * q + 0], a0);
            b0 = FDOT2(u.h2[0], w2b[4 * q + 0], b0);
            a1 = FDOT2(u.h2[1], w2a[4 * q + 1], a1);
            b1 = FDOT2(u.h2[1], w2b[4 * q + 1], b1);
            a0 = FDOT2(u.h2[2], w2a[4 * q + 2], a0);
            b0 = FDOT2(u.h2[2], w2b[4 * q + 2], b0);
            a1 = FDOT2(u.h2[3], w2a[4 * q + 3], a1);
            b1 = FDOT2(u.h2[3], w2b[4 * q + 3], b1);
        }
        float v0 = xc.x + a0 + a1;
        float v1 = xc.y + b0 + b1;
        v0 = 1.f / (1.f + __expf(-v0));
        v1 = 1.f / (1.f + __expf(-v1));
        val = make_float2(v0, v1);
        h2_t hv; hv[0] = (_Float16)v0; hv[1] = (_Float16)v1;
        h16[cur ^ 1][lane] = hv;                       // one ds_write_b32, conflict-free
        *(float2*)&out[(size_t)(b * 128 + i) * 128 + c0] = val;
        cur ^= 1;
    }
    *(float2*)&out[(size_t)B_ * S_ * H_ + b * 128 + c0] = val;
}

extern "C" void kernel_launch(void* const* d_in, const int* in_sizes, int n_in,
                              void* d_out, int out_size, void* d_ws, size_t ws_size,
                              hipStream_t stream) {
    const float* x  = (const float*)d_in[0];
    const int*   tc = (const int*)d_in[1];
    const int*   dc = (const int*)d_in[2];
    const int*   mk = (const int*)d_in[3];   // bool masks pushed as int32
    const float* tw = (const float*)d_in[4];
    const float* dw = (const float*)d_in[5];
    const float* hw = (const float*)d_in[6];
    float*    out = (float*)d_out;
    float*    wsf = (float*)d_ws;
    unsigned* wsi = (unsigned*)d_ws;
    char*     wsb = (char*)d_ws;

    int useY = (ws_size >= NEED_BYTES) ? 1 : 0;
    if (!useY)  // fallback path accumulates into XC with atomics -> needs zeroed XC
        hipMemsetAsync(wsb, 0, (size_t)262144 * 4, stream);

    k_hist1<<<dim3(256), dim3(256), 0, stream>>>(tc, dc, mk, wsi);
    k_scan_all<<<dim3(1), dim3(1024), 0, stream>>>(wsi);
    k_scatter<<<dim3(256), dim3(256), 0, stream>>>(tc, dc, mk, wsi, useY);
    k_phaseA<<<dim3(NS, 16), dim3(256), 0, stream>>>(x, tw, wsi, wsf);
    k_phaseB<<<dim3(NS, 16), dim3(256), 0, stream>>>(dw, wsi, wsf, useY);
    if (useY) k_reduce<<<dim3(2048), dim3(128), 0, stream>>>(wsi, wsf);
    k_recur<<<dim3(16), dim3(64), 0, stream>>>(hw, wsf, out);
}

// Round 9
// 155.929 us; speedup vs baseline: 1.2676x; 1.0553x over previous
//
#include <hip/hip_runtime.h>
#include <math.h>

// STRNN: B=16, S=128, D=64, K=64, H=128, NSLOT+1=97 slots.
//
// Pipeline (all f32 except recurrence dot in f16x2->f32 dot2):
//  k_hist1    : per-block LDS histograms of t-slot / d-slot / per-(b,i) counts
//  k_scan_all : exclusive scans -> per-(bin,block) bases + OFF_T/OFF_D/OFF_B
//  k_scatter  : one pass; LDS cursors; emits t-sorted entries, d-sorted refs, Y slots
//  k_phaseA   : per t-bucket GEMM  xt = x[b,j] @ Tw[t]   (Tw in LDS) -> XT[tpos][64]
//  k_phaseB   : per d-bucket GEMM  y = xt @ Dw[d] (Dw in LDS) -> Y[dstpos][128]
//  k_reduce   : XC[b,i,:] = sum of its contiguous Y rows
//  k_recur    : h = sigmoid(XC[b,i] + h@Wh); 2 waves/block, 1 col/lane,
//               Wh col in 64 half2 VGPRs (no spill), h in 512B LDS f16 dbuf,
//               XC prefetched 4 STEPS DEEP (named regs, x4-unrolled loop).
//
// ws requirement: ~104.3 MB for the atomic-free path (guarded; fallback = atomicAdd XC).

#define B_ 16
#define S_ 128
#define D_ 64
#define K_ 64
#define H_ 128
#define NS 97
#define MAXE 132096  // B * S*(S+1)/2  (upper bound on valid triples)

// u32/f32-index offsets into ws
#define XC_OFF 0                  // f32 [2048][128]
#define BH_T   262144             // u32 [97][256]  per-(bin,block) hist -> bases
#define BH_D   (BH_T + 24832)     // u32 [97][256]
#define CNT_T  (BH_D + 24832)     // u32 [97]
#define CNT_D  (CNT_T + 97)       // u32 [97]
#define CNT_B  (CNT_D + 97)       // u32 [2048]
#define OFF_T  (CNT_B + 2048)     // u32 [98] (last = total)
#define OFF_D  (OFF_T + 98)       // u32 [98]
#define OFF_B  (OFF_D + 98)       // u32 [2049]
#define ENT_T  316296             // u32 [MAXE] packed: b|i<<4|j<<11|t<<18|d<<25 (16B-aligned)
#define ENT_DX (ENT_T + MAXE)     // u32 [MAXE] xt-row index (t-sorted pos)
#define ENT_DP (ENT_DX + MAXE)    // u32 [MAXE] Y-row (dst-sorted pos) [or dst in fallback]
#define XT_OFF (ENT_DP + MAXE)    // f32 [MAXE][64]
#define Y_OFF  (XT_OFF + MAXE * 64)            // f32 [MAXE][128]
#define NEED_BYTES ((size_t)(Y_OFF + (size_t)MAXE * 128) * 4)

typedef _Float16 h2_t __attribute__((ext_vector_type(2)));

#if __has_builtin(__builtin_amdgcn_fdot2)
#define FDOT2(a, b, c) __builtin_amdgcn_fdot2((a), (b), (c), false)
#else
#define FDOT2(a, b, c) ((c) + (float)(a)[0] * (float)(b)[0] + (float)(a)[1] * (float)(b)[1])
#endif

// ---- binning: 256 blocks x 1024 elements (8 full (b,i) rows per block) ----

__global__ __launch_bounds__(256) void k_hist1(const int* __restrict__ tc,
                                               const int* __restrict__ dc,
                                               const int* __restrict__ mk,
                                               unsigned* wsi) {
    __shared__ unsigned ht[NS], hd[NS], hb[8];
    int tid = threadIdx.x, blk = blockIdx.x;
    if (tid < NS) { ht[tid] = 0; hd[tid] = 0; }
    if (tid < 8) hb[tid] = 0;
    __syncthreads();
    int base = blk * 1024;
    #pragma unroll
    for (int u = 0; u < 4; u++) {
        int idx = base + tid + u * 256;
        int i = (idx >> 7) & 127, j = idx & 127;
        if (j <= i && mk[idx] != 0) {
            atomicAdd(&ht[tc[idx]], 1u);
            atomicAdd(&hd[dc[idx]], 1u);
            atomicAdd(&hb[(idx >> 7) & 7], 1u);
        }
    }
    __syncthreads();
    if (tid < NS) {
        wsi[BH_T + tid * 256 + blk] = ht[tid];
        wsi[BH_D + tid * 256 + blk] = hd[tid];
    }
    if (tid < 8) wsi[CNT_B + blk * 8 + tid] = hb[tid];
}

template <int CH>
__device__ unsigned scan_region(unsigned* in, unsigned* out, int L, unsigned* s) {
    int tid = threadIdx.x;
    unsigned loc[CH], sum = 0;
    #pragma unroll
    for (int k = 0; k < CH; k++) {
        int idx = tid * CH + k;
        loc[k] = (idx < L) ? in[idx] : 0u;
        sum += loc[k];
    }
    s[tid] = sum;
    __syncthreads();
    for (int o = 1; o < 1024; o <<= 1) {
        unsigned a = (tid >= o) ? s[tid - o] : 0u;
        __syncthreads();
        s[tid] += a;
        __syncthreads();
    }
    unsigned total = s[1023];
    unsigned run = s[tid] - sum;
    __syncthreads();
    #pragma unroll
    for (int k = 0; k < CH; k++) {
        int idx = tid * CH + k;
        if (idx < L) { out[idx] = run; run += loc[k]; }
    }
    __syncthreads();
    return total;
}

__global__ __launch_bounds__(1024) void k_scan_all(unsigned* wsi) {
    __shared__ unsigned s[1024];
    int tid = threadIdx.x;

    unsigned totT = scan_region<25>(wsi + BH_T, wsi + BH_T, NS * 256, s);
    if (tid < NS) {
        unsigned b0 = wsi[BH_T + tid * 256];
        unsigned b1 = (tid < NS - 1) ? wsi[BH_T + (tid + 1) * 256] : totT;
        wsi[OFF_T + tid] = b0;
        wsi[CNT_T + tid] = b1 - b0;
    }
    if (tid == 0) wsi[OFF_T + NS] = totT;
    __syncthreads();

    unsigned totD = scan_region<25>(wsi + BH_D, wsi + BH_D, NS * 256, s);
    if (tid < NS) {
        unsigned b0 = wsi[BH_D + tid * 256];
        unsigned b1 = (tid < NS - 1) ? wsi[BH_D + (tid + 1) * 256] : totD;
        wsi[OFF_D + tid] = b0;
        wsi[CNT_D + tid] = b1 - b0;
    }
    if (tid == 0) wsi[OFF_D + NS] = totD;
    __syncthreads();

    unsigned totB = scan_region<2>(wsi + CNT_B, wsi + OFF_B, 2048, s);
    if (tid == 0) wsi[OFF_B + 2048] = totB;
}

__global__ __launch_bounds__(256) void k_scatter(const int* __restrict__ tc,
                                                 const int* __restrict__ dc,
                                                 const int* __restrict__ mk,
                                                 unsigned* wsi, int useY) {
    __shared__ unsigned ct[NS], cd[NS], cb[8];
    int tid = threadIdx.x, blk = blockIdx.x;
    if (tid < NS) {
        ct[tid] = wsi[BH_T + tid * 256 + blk];
        cd[tid] = wsi[BH_D + tid * 256 + blk];
    }
    if (tid < 8) cb[tid] = wsi[OFF_B + blk * 8 + tid];
    __syncthreads();
    int base = blk * 1024;
    #pragma unroll
    for (int u = 0; u < 4; u++) {
        int idx = base + tid + u * 256;
        int i = (idx >> 7) & 127, j = idx & 127, b = idx >> 14;
        if (j <= i && mk[idx] != 0) {
            unsigned t = (unsigned)tc[idx], d = (unsigned)dc[idx];
            unsigned tpos = atomicAdd(&ct[t], 1u);
            wsi[ENT_T + tpos] = (unsigned)b | ((unsigned)i << 4) | ((unsigned)j << 11)
                              | (t << 18) | (d << 25);
            unsigned dpos = atomicAdd(&cd[d], 1u);
            unsigned yp = useY ? atomicAdd(&cb[(idx >> 7) & 7], 1u) : (unsigned)(idx >> 7);
            wsi[ENT_DX + dpos] = tpos;
            wsi[ENT_DP + dpos] = yp;
        }
    }
}

// phase A: xt[entry][kk] = sum_dd x[b,j][dd] * Tw[t][dd][kk]
__global__ __launch_bounds__(256) void k_phaseA(const float* __restrict__ x,
                                                const float* __restrict__ tw,
                                                unsigned* wsi, float* wsf) {
    int t = blockIdx.x, c = blockIdx.y;
    int rows = (int)wsi[CNT_T + t] - c * 128;
    if (rows <= 0) return;
    if (rows > 128) rows = 128;
    unsigned base = wsi[OFF_T + t] + c * 128;

    __shared__ float stw[4096];     // Tw[t] row-major [dd][kk]
    __shared__ float sx[8192];      // x rows, XOR-swizzled in 4-float units
    __shared__ unsigned ent[128];
    int tid = threadIdx.x;

    const float4* twg = (const float4*)(tw + t * 4096);
    float4* stw4 = (float4*)stw;
    #pragma unroll
    for (int q = 0; q < 4; q++) stw4[q * 256 + tid] = twg[q * 256 + tid];
    if (tid < 128) ent[tid] = (tid < rows) ? wsi[ENT_T + base + tid] : 0u;
    __syncthreads();

    int lane16 = tid & 15, rquot = tid >> 4;
    #pragma unroll
    for (int p = 0; p < 8; p++) {
        int r = p * 16 + rquot;
        float4 v = make_float4(0.f, 0.f, 0.f, 0.f);
        if (r < rows) {
            unsigned e = ent[r];
            int b = e & 15, j = (e >> 11) & 127;
            v = *(const float4*)(x + (b * S_ + j) * D_ + lane16 * 4);
        }
        int col4 = lane16 ^ (r & 15);
        float* dst = &sx[r * 64 + col4 * 4];
        dst[0] = v.x; dst[1] = v.y; dst[2] = v.z; dst[3] = v.w;
    }
    __syncthreads();

    int rgrp = tid & 15, cgrp = tid >> 4;   // 8 rows (rgrp+16i) x 4 cols (cgrp*4..)
    float4 acc[8];
    #pragma unroll
    for (int i = 0; i < 8; i++) acc[i] = make_float4(0.f, 0.f, 0.f, 0.f);
    #pragma unroll 4
    for (int dd = 0; dd < 64; dd++) {
        float4 w = stw4[dd * 16 + cgrp];
        int s_idx = (((dd >> 2) ^ rgrp) << 2) + (dd & 3);
        #pragma unroll
        for (int i = 0; i < 8; i++) {
            float a = sx[(rgrp + 16 * i) * 64 + s_idx];
            acc[i].x += a * w.x; acc[i].y += a * w.y;
            acc[i].z += a * w.z; acc[i].w += a * w.w;
        }
    }
    float* XT = wsf + XT_OFF;
    #pragma unroll
    for (int i = 0; i < 8; i++) {
        int r = rgrp + 16 * i;
        if (r < rows) *(float4*)(XT + (size_t)(base + r) * 64 + cgrp * 4) = acc[i];
    }
}

// phase B: y[hh] = sum_kk xt[entry][kk] * Dw[d][kk][hh]; write to Y[dstpos] (or atomic XC)
__global__ __launch_bounds__(256) void k_phaseB(const float* __restrict__ dw,
                                                unsigned* wsi, float* wsf, int useY) {
    int d = blockIdx.x, c = blockIdx.y;
    int rows = (int)wsi[CNT_D + d] - c * 128;
    if (rows <= 0) return;
    if (rows > 128) rows = 128;
    unsigned base = wsi[OFF_D + d] + c * 128;

    __shared__ float sdw[8192];     // Dw[d] row-major [kk][hh]
    __shared__ float sx[8192];      // xt rows, swizzled
    __shared__ unsigned entx[128];
    __shared__ unsigned entp[128];
    int tid = threadIdx.x;

    const float4* dwg = (const float4*)(dw + (size_t)d * 8192);
    float4* sdw4 = (float4*)sdw;
    #pragma unroll
    for (int q = 0; q < 8; q++) sdw4[q * 256 + tid] = dwg[q * 256 + tid];
    if (tid < 128) {
        entx[tid] = (tid < rows) ? wsi[ENT_DX + base + tid] : 0u;
        entp[tid] = (tid < rows) ? wsi[ENT_DP + base + tid] : 0u;
    }
    __syncthreads();

    const float* XT = wsf + XT_OFF;
    int lane16 = tid & 15, rquot = tid >> 4;
    #pragma unroll
    for (int p = 0; p < 8; p++) {
        int r = p * 16 + rquot;
        float4 v = make_float4(0.f, 0.f, 0.f, 0.f);
        if (r < rows) {
            unsigned pos = entx[r];
            v = *(const float4*)(XT + (size_t)pos * 64 + lane16 * 4);
        }
        int col4 = lane16 ^ (r & 15);
        float* dst2 = &sx[r * 64 + col4 * 4];
        dst2[0] = v.x; dst2[1] = v.y; dst2[2] = v.z; dst2[3] = v.w;
    }
    __syncthreads();

    int rgrp = tid & 15, cgrp = tid >> 4;   // 8 rows x 8 cols (cgrp*8..)
    float4 a0[8], a1[8];
    #pragma unroll
    for (int i = 0; i < 8; i++) {
        a0[i] = make_float4(0.f, 0.f, 0.f, 0.f);
        a1[i] = make_float4(0.f, 0.f, 0.f, 0.f);
    }
    #pragma unroll 2
    for (int kk = 0; kk < 64; kk++) {
        float4 w0 = sdw4[kk * 32 + cgrp * 2];
        float4 w1 = sdw4[kk * 32 + cgrp * 2 + 1];
        int s_idx = (((kk >> 2) ^ rgrp) << 2) + (kk & 3);
        #pragma unroll
        for (int i = 0; i < 8; i++) {
            float a = sx[(rgrp + 16 * i) * 64 + s_idx];
            a0[i].x += a * w0.x; a0[i].y += a * w0.y; a0[i].z += a * w0.z; a0[i].w += a * w0.w;
            a1[i].x += a * w1.x; a1[i].y += a * w1.y; a1[i].z += a * w1.z; a1[i].w += a * w1.w;
        }
    }
    if (useY) {
        float* Y = wsf + Y_OFF;
        #pragma unroll
        for (int i = 0; i < 8; i++) {
            int r = rgrp + 16 * i;
            if (r < rows) {
                float* p = Y + (size_t)entp[r] * 128 + cgrp * 8;
                *(float4*)p = a0[i];
                *(float4*)(p + 4) = a1[i];
            }
        }
    } else {
        float* XC = wsf + XC_OFF;
        #pragma unroll
        for (int i = 0; i < 8; i++) {
            int r = rgrp + 16 * i;
            if (r < rows) {
                float* p = XC + (size_t)entp[r] * 128 + cgrp * 8;
                atomicAdd(p + 0, a0[i].x); atomicAdd(p + 1, a0[i].y);
                atomicAdd(p + 2, a0[i].z); atomicAdd(p + 3, a0[i].w);
                atomicAdd(p + 4, a1[i].x); atomicAdd(p + 5, a1[i].y);
                atomicAdd(p + 6, a1[i].z); atomicAdd(p + 7, a1[i].w);
            }
        }
    }
}

// XC[b,i,:] = sum of this (b,i)'s contiguous Y rows
__global__ __launch_bounds__(128) void k_reduce(unsigned* wsi, float* wsf) {
    int bi = blockIdx.x, tid = threadIdx.x;
    unsigned n = wsi[CNT_B + bi], off = wsi[OFF_B + bi];
    const float* Yp = wsf + Y_OFF + (size_t)off * 128 + tid;
    float a0 = 0.f, a1 = 0.f, a2 = 0.f, a3 = 0.f;
    unsigned e = 0;
    for (; e + 4 <= n; e += 4) {
        a0 += Yp[(size_t)e * 128];
        a1 += Yp[(size_t)(e + 1) * 128];
        a2 += Yp[(size_t)(e + 2) * 128];
        a3 += Yp[(size_t)(e + 3) * 128];
    }
    for (; e < n; e++) a0 += Yp[(size_t)e * 128];
    wsf[XC_OFF + (size_t)bi * 128 + tid] = (a0 + a1) + (a2 + a3);
}

// recurrence: h_new = sigmoid(XC[b,i] + h @ Wh); one block (128 thr = 2 waves) per b.
// Lane owns col = wv*64+lane; Wh column in VGPRs as 64 half2 (no spill).
// h in 512B LDS f16, double-buffered; loop unrolled x4 so buffer index is static
// and XC is prefetched FOUR steps ahead into named registers (hides HBM latency).
#define RSTEP(XCREG, IDX, CURB)                                                \
    {                                                                          \
        float xc_use = XCREG;                                                  \
        if (i + 4 + (IDX) < 128) XCREG = XC[(i + 4 + (IDX)) * 128];            \
        const float4* hb = (const float4*)&h16[CURB][0];                       \
        float a0 = 0.f, a1 = 0.f, a2 = 0.f, a3 = 0.f;                          \
        _Pragma("unroll")                                                      \
        for (int q = 0; q < 16; q++) {                                         \
            union { float4 f4; h2_t h2[4]; } u;                                \
            u.f4 = hb[q];                                                      \
            a0 = FDOT2(u.h2[0], w2[4 * q + 0], a0);                            \
            a1 = FDOT2(u.h2[1], w2[4 * q + 1], a1);                            \
            a2 = FDOT2(u.h2[2], w2[4 * q + 2], a2);                            \
            a3 = FDOT2(u.h2[3], w2[4 * q + 3], a3);                            \
        }                                                                      \
        float v = xc_use + (a0 + a1) + (a2 + a3);                              \
        v = 1.f / (1.f + __expf(-v));                                          \
        val = v;                                                               \
        ((_Float16*)&h16[(CURB) ^ 1][0])[col] = (_Float16)v;                   \
        out[(size_t)(b * 128 + i + (IDX)) * 128 + col] = v;                    \
        __syncthreads();                                                       \
    }

__global__ __launch_bounds__(128) void k_recur(const float* __restrict__ hw,
                                               const float* __restrict__ wsf,
                                               float* __restrict__ out) {
    int b = blockIdx.x;
    __shared__ h2_t h16[2][64];         // [buf][64 half2] = 128 halves
    int tid = threadIdx.x;
    int lane = tid & 63, wv = tid >> 6;
    int col = wv * 64 + lane;

    h2_t w2[64];
    #pragma unroll
    for (int m = 0; m < 64; m++) {
        h2_t p;
        p[0] = (_Float16)hw[(2 * m) * 128 + col];       // coalesced across lanes
        p[1] = (_Float16)hw[(2 * m + 1) * 128 + col];
        w2[m] = p;
    }
    if (tid < 64) h16[0][tid] = (h2_t)(_Float16)0.f;
    __syncthreads();

    const float* XC = wsf + XC_OFF + (size_t)b * 128 * 128 + col;
    float xc0 = XC[0 * 128], xc1 = XC[1 * 128], xc2 = XC[2 * 128], xc3 = XC[3 * 128];
    float val = 0.f;
    for (int i = 0; i < 128; i += 4) {
        RSTEP(xc0, 0, 0)
        RSTEP(xc1, 1, 1)
        RSTEP(xc2, 2, 0)
        RSTEP(xc3, 3, 1)
    }
    out[(size_t)B_ * S_ * H_ + b * 128 + col] = val;
}

extern "C" void kernel_launch(void* const* d_in, const int* in_sizes, int n_in,
                              void* d_out, int out_size, void* d_ws, size_t ws_size,
                              hipStream_t stream) {
    const float* x  = (const float*)d_in[0];
    const int*   tc = (const int*)d_in[1];
    const int*   dc = (const int*)d_in[2];
    const int*   mk = (const int*)d_in[3];   // bool masks pushed as int32
    const float* tw = (const float*)d_in[4];
    const float* dw = (const float*)d_in[5];
    const float* hw = (const float*)d_in[6];
    float*    out = (float*)d_out;
    float*    wsf = (float*)d_ws;
    unsigned* wsi = (unsigned*)d_ws;
    char*     wsb = (char*)d_ws;

    int useY = (ws_size >= NEED_BYTES) ? 1 : 0;
    if (!useY)  // fallback path accumulates into XC with atomics -> needs zeroed XC
        hipMemsetAsync(wsb, 0, (size_t)262144 * 4, stream);

    k_hist1<<<dim3(256), dim3(256), 0, stream>>>(tc, dc, mk, wsi);
    k_scan_all<<<dim3(1), dim3(1024), 0, stream>>>(wsi);
    k_scatter<<<dim3(256), dim3(256), 0, stream>>>(tc, dc, mk, wsi, useY);
    k_phaseA<<<dim3(NS, 16), dim3(256), 0, stream>>>(x, tw, wsi, wsf);
    k_phaseB<<<dim3(NS, 16), dim3(256), 0, stream>>>(dw, wsi, wsf, useY);
    if (useY) k_reduce<<<dim3(2048), dim3(128), 0, stream>>>(wsi, wsf);
    k_recur<<<dim3(16), dim3(128), 0, stream>>>(hw, wsf, out);
}